// Round 5
// baseline (4209.575 us; speedup 1.0000x reference)
//
#include <hip/hip_runtime.h>
#include <math.h>

// ---------------------------------------------------------------------------
// FeatureEncoder R5: register-tiled fp32 convs (4 px x OCPT oc per thread ->
// 4 FMAs per weight fetch), LDS input staging with fused norm+relu,
// K-split (no atomics) for grid-starved layers L2/L3/L4 with per-plane
// reduce+bias+stats pass. Stats for other layers via block partials +
// stat_reduce (R4 scheme, no global atomics).
// ---------------------------------------------------------------------------

#define IDIV(a, b) (((a) + (b) - 1) / (b))

__device__ __forceinline__ int reflect_i(int i, int n) {
    i = i < 0 ? -i : i;
    return i >= n ? 2 * n - 2 - i : i;
}

// block-level (sum,sumsq) reduction for OCPT channels -> partial store
template <int OCPT>
__device__ __forceinline__ void stats_block_store(
    const float* sv, const float* ssv, float* __restrict__ spart,
    float* __restrict__ sspart, int P, int tile, int pc0) {
    __shared__ float redS[OCPT], redSS[OCPT];
    if (threadIdx.x < OCPT) { redS[threadIdx.x] = 0.f; redSS[threadIdx.x] = 0.f; }
    __syncthreads();
    int lane = threadIdx.x & 63;
#pragma unroll
    for (int j = 0; j < OCPT; ++j) {
        float s = sv[j], ss = ssv[j];
#pragma unroll
        for (int o = 32; o > 0; o >>= 1) {
            s += __shfl_down(s, o);
            ss += __shfl_down(ss, o);
        }
        if (lane == 0) { atomicAdd(&redS[j], s); atomicAdd(&redSS[j], ss); }
    }
    __syncthreads();
    if (threadIdx.x < OCPT) {
        spart[(size_t)tile * P + pc0 + threadIdx.x] = redS[threadIdx.x];
        sspart[(size_t)tile * P + pc0 + threadIdx.x] = redSS[threadIdx.x];
    }
}

// fold [nT][P] partials into ssum/sssum; one wavefront per plane
__global__ __launch_bounds__(64) void stat_reduce(
    const float* __restrict__ sp, const float* __restrict__ ssp,
    float* __restrict__ s, float* __restrict__ ss, int P, int nT, int off) {
    int p = blockIdx.x;
    float a = 0.f, b = 0.f;
    for (int t = threadIdx.x; t < nT; t += 64) {
        a += sp[(size_t)t * P + p];
        b += ssp[(size_t)t * P + p];
    }
#pragma unroll
    for (int o = 32; o > 0; o >>= 1) {
        a += __shfl_down(a, o);
        b += __shfl_down(b, o);
    }
    if (threadIdx.x == 0) { s[off + p] = a; ss[off + p] = b; }
}

// sum KS k-split partials + bias -> y, plus per-plane stats (one block/plane)
__global__ __launch_bounds__(256) void ksplit_reduce(
    const float* __restrict__ part, const float* __restrict__ b,
    float* __restrict__ y, float* __restrict__ ssum, float* __restrict__ sssum,
    int off, int Cout, int PE, size_t outSize, int KS) {
    int p = blockIdx.x;  // plane = n*Cout + oc
    float bias = b[p % Cout];
    const float* pp = part + (size_t)p * PE;
    float* yp = y + (size_t)p * PE;
    float s = 0.f, ss = 0.f;
    for (int i = threadIdx.x; i < PE; i += 256) {
        float v = bias;
        for (int k = 0; k < KS; ++k) v += pp[(size_t)k * outSize + i];
        yp[i] = v;
        s += v;
        ss += v * v;
    }
#pragma unroll
    for (int o = 32; o > 0; o >>= 1) {
        s += __shfl_down(s, o);
        ss += __shfl_down(ss, o);
    }
    __shared__ float red[8];
    int wid = threadIdx.x >> 6;
    if ((threadIdx.x & 63) == 0) { red[wid] = s; red[4 + wid] = ss; }
    __syncthreads();
    if (threadIdx.x == 0) {
        ssum[off + p] = red[0] + red[1] + red[2] + red[3];
        sssum[off + p] = red[4] + red[5] + red[6] + red[7];
    }
}

// ---------------- 7x7 same-conv, reflect pad 3 (L0, L7) ----------------
// tile 16 rows x 64 cols out; thread = (ty, tc): 4 contiguous cols x OCPT oc.
template <int CIN, int ICB, int OCPT, bool NORM, bool TANH>
__global__ __launch_bounds__(256) void conv7_v2(
    const float* __restrict__ x, const float* __restrict__ w,
    const float* __restrict__ b, float* __restrict__ y,
    const float* __restrict__ in_s, const float* __restrict__ in_ss,
    float rcp_plane_in, int in_off,
    float* __restrict__ spart, float* __restrict__ sspart, int P,
    int Cout, int H, int W) {
    constexpr int RST = 72;            // row stride (floats), 22 rows x 70 cols used
    constexpr int ICST = 22 * RST;
    __shared__ float tile[ICB * ICST];
    int tc = threadIdx.x & 15, ty = threadIdx.x >> 4;
    int tilesX = IDIV(W, 64);
    int bx = blockIdx.x % tilesX, by = blockIdx.x / tilesX;
    int oc0 = blockIdx.y * OCPT, n = blockIdx.z;
    int row0 = by * 16 - 3, col0 = bx * 64 - 3;
    int oh = by * 16 + ty;
    int ow0 = bx * 64 + tc * 4;

    float acc[OCPT][4];
#pragma unroll
    for (int j = 0; j < OCPT; ++j)
#pragma unroll
        for (int p = 0; p < 4; ++p) acc[j][p] = 0.f;

    for (int ic0 = 0; ic0 < CIN; ic0 += ICB) {
        __syncthreads();
        for (int icl = 0; icl < ICB; ++icl) {
            int ic = ic0 + icl;
            float m = 0.f, iv = 1.f;
            if (NORM) {
                int pc = in_off + n * CIN + ic;
                m = in_s[pc] * rcp_plane_in;
                iv = rsqrtf(in_ss[pc] * rcp_plane_in - m * m + 1e-5f);
            }
            const float* base = x + (size_t)(n * CIN + ic) * H * W;
            for (int t = threadIdx.x; t < 1540; t += 256) {
                int r = t / 70, c = t % 70;
                int gr = reflect_i(row0 + r, H);
                int gc = reflect_i(col0 + c, W);
                float raw = base[(size_t)gr * W + gc];
                tile[icl * ICST + r * RST + c] = NORM ? fmaxf(0.f, (raw - m) * iv) : raw;
            }
        }
        __syncthreads();
#pragma unroll
        for (int icl = 0; icl < ICB; ++icl) {
            const float* lbase = tile + icl * ICST + (size_t)0;
#pragma unroll
            for (int kh = 0; kh < 7; ++kh) {
                float rf[10];
                const float* lrow = lbase + (ty + kh) * RST + tc * 4;
#pragma unroll
                for (int q = 0; q < 10; ++q) rf[q] = lrow[q];
#pragma unroll
                for (int j = 0; j < OCPT; ++j) {
                    const float* wj = w + (((size_t)(oc0 + j) * CIN + ic0 + icl) * 7 + kh) * 7;
#pragma unroll
                    for (int kw = 0; kw < 7; ++kw) {
                        float wv = wj[kw];
#pragma unroll
                        for (int p = 0; p < 4; ++p) acc[j][p] += rf[kw + p] * wv;
                    }
                }
            }
        }
    }

    float sv[OCPT], ssv[OCPT];
#pragma unroll
    for (int j = 0; j < OCPT; ++j) {
        float s = 0.f, ss = 0.f;
        float bb = b[oc0 + j];
        float* yp = y + ((size_t)(n * Cout + oc0 + j) * H + oh) * W + ow0;
#pragma unroll
        for (int p = 0; p < 4; ++p) {
            float r = acc[j][p] + bb;
            if (TANH) r = tanhf(r);
            bool ok = (oh < H) && (ow0 + p < W);
            if (ok) { yp[p] = r; s += r; ss += r * r; }
        }
        sv[j] = s; ssv[j] = ss;
    }
    if (!TANH)
        stats_block_store<OCPT>(sv, ssv, spart, sspart, P, blockIdx.x, n * Cout + oc0);
}

// ---------------- 3x3 stride-2 pad-1 conv (L1,L2,L3) ----------------
// tile TH x TW out; thread covers 4 contiguous out cols x OCPT oc.
// LDS: parity-split cols (even sec + odd sec), so stride-2 reads are dense.
template <int CIN, int ICB, int OCPT, int TH, int TW, int KS>
__global__ __launch_bounds__(256) void conv3s2_v2(
    const float* __restrict__ x, const float* __restrict__ w,
    const float* __restrict__ b, float* __restrict__ y,
    const float* __restrict__ in_s, const float* __restrict__ in_ss,
    float rcp_plane_in, int in_off,
    float* __restrict__ spart, float* __restrict__ sspart, int P,
    float* __restrict__ part, size_t outSize,
    int Cout, int Hin, int Win, int Hout, int Wout) {
    constexpr int TC = TW / 4;
    constexpr int IR = 2 * TH + 1;
    constexpr int IC = 2 * TW + 1;
    constexpr int SEC = ((TW + 1 + 3) / 4) * 4;  // even-col section, 16B aligned
    constexpr int RST = 2 * SEC;
    constexpr int ICST = IR * RST;
    __shared__ float tile[ICB * ICST];
    int tc = threadIdx.x % TC, ty = threadIdx.x / TC;
    int tilesX = Wout / TW;
    int bx = blockIdx.x % tilesX, by = blockIdx.x / tilesX;
    int ks = blockIdx.y % KS, ocg = blockIdx.y / KS;
    int oc0 = ocg * OCPT, n = blockIdx.z;
    int row0 = by * TH * 2 - 1, col0 = bx * TW * 2 - 1;
    int oh = by * TH + ty;
    int ow0 = bx * TW + tc * 4;

    float acc[OCPT][4];
#pragma unroll
    for (int j = 0; j < OCPT; ++j)
#pragma unroll
        for (int p = 0; p < 4; ++p) acc[j][p] = 0.f;

    const int icbeg = ks * (CIN / KS), icend = (ks + 1) * (CIN / KS);
    for (int ic0 = icbeg; ic0 < icend; ic0 += ICB) {
        __syncthreads();
        for (int icl = 0; icl < ICB; ++icl) {
            int ic = ic0 + icl;
            int pc = in_off + n * CIN + ic;
            float m = in_s[pc] * rcp_plane_in;
            float iv = rsqrtf(in_ss[pc] * rcp_plane_in - m * m + 1e-5f);
            const float* base = x + (size_t)(n * CIN + ic) * Hin * Win;
            for (int t = threadIdx.x; t < IR * IC; t += 256) {
                int r = t / IC, c = t % IC;
                int gr = row0 + r, gc = col0 + c;
                float v = 0.f;
                if (gr >= 0 && gr < Hin && gc >= 0 && gc < Win)
                    v = fmaxf(0.f, (base[(size_t)gr * Win + gc] - m) * iv);
                tile[icl * ICST + r * RST + (c & 1) * SEC + (c >> 1)] = v;
            }
        }
        __syncthreads();
#pragma unroll
        for (int icl = 0; icl < ICB; ++icl) {
#pragma unroll
            for (int kh = 0; kh < 3; ++kh) {
                const float* lrow = tile + icl * ICST + (2 * ty + kh) * RST;
                float E[5], O[4];
#pragma unroll
                for (int q = 0; q < 5; ++q) E[q] = lrow[4 * tc + q];
#pragma unroll
                for (int q = 0; q < 4; ++q) O[q] = lrow[SEC + 4 * tc + q];
#pragma unroll
                for (int j = 0; j < OCPT; ++j) {
                    const float* wj = w + (((size_t)(oc0 + j) * CIN + ic0 + icl) * 3 + kh) * 3;
                    float w0 = wj[0], w1 = wj[1], w2 = wj[2];
#pragma unroll
                    for (int p = 0; p < 4; ++p)
                        acc[j][p] += E[p] * w0 + O[p] * w1 + E[p + 1] * w2;
                }
            }
        }
    }

    if (KS == 1) {
        float sv[OCPT], ssv[OCPT];
#pragma unroll
        for (int j = 0; j < OCPT; ++j) {
            float bb = b[oc0 + j];
            float s = 0.f, ss = 0.f;
            float* yp = y + ((size_t)(n * Cout + oc0 + j) * Hout + oh) * Wout + ow0;
#pragma unroll
            for (int p = 0; p < 4; ++p) {
                float r = acc[j][p] + bb;
                yp[p] = r; s += r; ss += r * r;
            }
            sv[j] = s; ssv[j] = ss;
        }
        stats_block_store<OCPT>(sv, ssv, spart, sspart, P, blockIdx.x, n * Cout + oc0);
    } else {
#pragma unroll
        for (int j = 0; j < OCPT; ++j) {
            float* pp = part + (size_t)ks * outSize +
                        ((size_t)(n * Cout + oc0 + j) * Hout + oh) * Wout + ow0;
#pragma unroll
            for (int p = 0; p < 4; ++p) pp[p] = acc[j][p];
        }
    }
}

// ---------------- 3x3 s2 transposed conv, quad form (L4,L5,L6) ----------------
// quad-tile 32x32 per block; thread = (i,j) covers 2x2 quads (4x4 out pixels).
template <int CIN, int ICB, int OCPT, int KS>
__global__ __launch_bounds__(256) void convt3_v2(
    const float* __restrict__ x, const float* __restrict__ w,
    const float* __restrict__ b, float* __restrict__ y,
    const float* __restrict__ in_s, const float* __restrict__ in_ss,
    float rcp_plane_in, int in_off,
    float* __restrict__ spart, float* __restrict__ sspart, int P,
    float* __restrict__ part, size_t outSize,
    int Cout, int Hin, int Win, int Hout, int Wout) {
    constexpr int RST = 36;
    constexpr int ICST = 33 * RST;
    __shared__ float tile[ICB * ICST];
    int j16 = threadIdx.x & 15, i16 = threadIdx.x >> 4;
    int tilesX = IDIV(Win, 32);
    int bx = blockIdx.x % tilesX, by = blockIdx.x / tilesX;
    int ks = blockIdx.y % KS, ocg = blockIdx.y / KS;
    int oc0 = ocg * OCPT, n = blockIdx.z;
    int qy0 = by * 32, qx0 = bx * 32;

    float acc[OCPT][4][4];  // [oc][quad a*2+b][subpix]
#pragma unroll
    for (int j = 0; j < OCPT; ++j)
#pragma unroll
        for (int q = 0; q < 4; ++q)
#pragma unroll
            for (int s = 0; s < 4; ++s) acc[j][q][s] = 0.f;

    const int icbeg = ks * (CIN / KS), icend = (ks + 1) * (CIN / KS);
    for (int ic0 = icbeg; ic0 < icend; ic0 += ICB) {
        __syncthreads();
        for (int icl = 0; icl < ICB; ++icl) {
            int ic = ic0 + icl;
            int pc = in_off + n * CIN + ic;
            float m = in_s[pc] * rcp_plane_in;
            float iv = rsqrtf(in_ss[pc] * rcp_plane_in - m * m + 1e-5f);
            const float* base = x + (size_t)(n * CIN + ic) * Hin * Win;
            for (int t = threadIdx.x; t < 33 * 33; t += 256) {
                int r = t / 33, c = t % 33;
                int gr = qy0 + r, gc = qx0 + c;
                float v = 0.f;
                if (gr < Hin && gc < Win)
                    v = fmaxf(0.f, (base[(size_t)gr * Win + gc] - m) * iv);
                tile[icl * ICST + r * RST + c] = v;
            }
        }
        __syncthreads();
#pragma unroll
        for (int icl = 0; icl < ICB; ++icl) {
            float vr[3][3];
#pragma unroll
            for (int dr = 0; dr < 3; ++dr)
#pragma unroll
                for (int dc = 0; dc < 3; ++dc)
                    vr[dr][dc] = tile[icl * ICST + (2 * i16 + dr) * RST + 2 * j16 + dc];
#pragma unroll
            for (int j = 0; j < OCPT; ++j) {
                const float* wj = w + ((size_t)(ic0 + icl) * Cout + oc0 + j) * 9;
                float w0 = wj[0], w1 = wj[1], w2 = wj[2];
                float w3 = wj[3], w4 = wj[4], w5 = wj[5];
                float w6 = wj[6], w7 = wj[7], w8 = wj[8];
#pragma unroll
                for (int a = 0; a < 2; ++a) {
#pragma unroll
                    for (int bq = 0; bq < 2; ++bq) {
                        float v00 = vr[a][bq], v01 = vr[a][bq + 1];
                        float v10 = vr[a + 1][bq], v11 = vr[a + 1][bq + 1];
                        float* ap = acc[j][a * 2 + bq];
                        ap[0] += w4 * v00;
                        ap[1] += w5 * v00 + w3 * v01;
                        ap[2] += w7 * v00 + w1 * v10;
                        ap[3] += w8 * v00 + w6 * v01 + w2 * v10 + w0 * v11;
                    }
                }
            }
        }
    }

    float sv[OCPT], ssv[OCPT];
#pragma unroll
    for (int j = 0; j < OCPT; ++j) { sv[j] = 0.f; ssv[j] = 0.f; }
#pragma unroll
    for (int a = 0; a < 2; ++a) {
#pragma unroll
        for (int bq = 0; bq < 2; ++bq) {
            int qy = qy0 + 2 * i16 + a, qx = qx0 + 2 * j16 + bq;
            bool v0 = (qy < Hin) && (qx < Win);
            bool mx = v0 && (2 * qx + 1 < Wout), my = v0 && (2 * qy + 1 < Hout);
            bool mxy = mx && (2 * qy + 1 < Hout);
            int oh = 2 * qy, ow = 2 * qx;
#pragma unroll
            for (int j = 0; j < OCPT; ++j) {
                const float* ap = acc[j][a * 2 + bq];
                if (KS == 1) {
                    float bb = b[oc0 + j];
                    float* yp = y + ((size_t)(n * Cout + oc0 + j) * Hout + oh) * Wout + ow;
                    if (v0) { float t = ap[0] + bb; yp[0] = t; sv[j] += t; ssv[j] += t * t; }
                    if (mx) { float t = ap[1] + bb; yp[1] = t; sv[j] += t; ssv[j] += t * t; }
                    if (my) { float t = ap[2] + bb; yp[Wout] = t; sv[j] += t; ssv[j] += t * t; }
                    if (mxy) { float t = ap[3] + bb; yp[Wout + 1] = t; sv[j] += t; ssv[j] += t * t; }
                } else {
                    float* pp = part + (size_t)ks * outSize +
                                ((size_t)(n * Cout + oc0 + j) * Hout + oh) * Wout + ow;
                    if (v0) pp[0] = ap[0];
                    if (mx) pp[1] = ap[1];
                    if (my) pp[Wout] = ap[2];
                    if (mxy) pp[Wout + 1] = ap[3];
                }
            }
        }
    }
    if (KS == 1)
        stats_block_store<OCPT>(sv, ssv, spart, sspart, P, blockIdx.x, n * Cout + oc0);
}

// ---------------- misc ----------------
__global__ void zero_buf(float* __restrict__ p, int n) {
    int i = blockIdx.x * 256 + threadIdx.x;
    if (i < n) p[i] = 0.f;
}

__global__ void seg_accum(const float* __restrict__ a7, const int* __restrict__ inst,
                          float* __restrict__ bins, int HW) {
    __shared__ float ls[128];
    for (int i = threadIdx.x; i < 128; i += 256) ls[i] = 0.f;
    __syncthreads();
    int n = blockIdx.y;
    int i = blockIdx.x * 256 + threadIdx.x;
    if (i < HW) {
        int id = inst[(size_t)n * HW + i];
        const float* p = a7 + (size_t)n * 3 * HW + i;
        atomicAdd(&ls[id * 3 + 0], p[0]);
        atomicAdd(&ls[id * 3 + 1], p[HW]);
        atomicAdd(&ls[id * 3 + 2], p[2 * (size_t)HW]);
        atomicAdd(&ls[96 + id], 1.0f);
    }
    __syncthreads();
    for (int i2 = threadIdx.x; i2 < 128; i2 += 256)
        if (ls[i2] != 0.f) atomicAdd(&bins[i2], ls[i2]);
}

__global__ void seg_scatter(const float* __restrict__ bins, const int* __restrict__ inst,
                            float* __restrict__ out, int HW) {
    int n = blockIdx.y;
    int i = blockIdx.x * 256 + threadIdx.x;
    if (i >= HW) return;
    int id = inst[(size_t)n * HW + i];
    float c = fmaxf(bins[96 + id], 1.0f);
    out[((size_t)n * 3 + 0) * HW + i] = bins[id * 3 + 0] / c;
    out[((size_t)n * 3 + 1) * HW + i] = bins[id * 3 + 1] / c;
    out[((size_t)n * 3 + 2) * HW + i] = bins[id * 3 + 2] / c;
}

// ---------------------------------------------------------------------------
extern "C" void kernel_launch(void* const* d_in, const int* in_sizes, int n_in,
                              void* d_out, int out_size, void* d_ws, size_t ws_size,
                              hipStream_t stream) {
    const float* x = (const float*)d_in[0];
    const int* inst = (const int*)d_in[1];
    const float* W[8];
    const float* B[8];
    for (int i = 0; i < 8; ++i) {
        W[i] = (const float*)d_in[2 + 2 * i];
        B[i] = (const float*)d_in[3 + 2 * i];
    }
    float* ws = (float*)d_ws;

    const size_t S = 25165824;  // activation arena floats
    float* a0 = ws;                  // [8,32,256,256]  0 .. 16.78M
    float* a1 = ws + 16777216;       // [8,64,128,128]  16.78M .. 25.17M
    float* a2 = ws;                  // [8,128,64,64]   0 .. 4.19M
    float* a3 = ws + 23068672;       // [8,256,32,32]   23.07M .. 25.17M
    float* a4 = ws;                  // [8,128,63,63]   0 .. 4.06M
    float* a5 = ws + 17165824;       // [8,64,125,125]  17.17M .. 25.17M
    float* a6 = ws;                  // [8,32,249,249]  0 .. 15.87M
    float* a7 = ws + 23677800;       // [8,3,249,249]
    float* PART = ws + 4194304;      // k-split partials (fits free arena gaps)
    float* ssum = ws + S;            // 5632
    float* sssum = ssum + 5632;      // 5632
    float* bins = sssum + 5632;      // 128
    float* spart = bins + 128;       // 151552
    float* sspart = spart + 151552;
    const int OFF0 = 0, OFF1 = 256, OFF2 = 768, OFF3 = 1792, OFF4 = 3840, OFF5 = 4864, OFF6 = 5376;
    const int PO0 = 0, PO1 = 65536, PO5 = 126976, PO6 = 135168;

    zero_buf<<<dim3(1), 256, 0, stream>>>(bins, 128);

    // L0: 7x7 reflect, 3->32, 256. tiles 4x16=64, ocg 4, n 8 -> 2048 blocks
    conv7_v2<3, 3, 8, false, false><<<dim3(64, 4, 8), 256, 0, stream>>>(
        x, W[0], B[0], a0, nullptr, nullptr, 0.f, 0, spart + PO0, sspart + PO0, 256, 32, 256, 256);
    stat_reduce<<<dim3(256), 64, 0, stream>>>(spart + PO0, sspart + PO0, ssum, sssum, 256, 64, OFF0);

    // L1: 3x3 s2, 32->64, 256->128. tile 16x64: tiles 2x8=16, ocg 8, n 8 -> 1024
    conv3s2_v2<32, 2, 8, 16, 64, 1><<<dim3(16, 8, 8), 256, 0, stream>>>(
        a0, W[1], B[1], a1, ssum, sssum, 1.f / 65536.f, OFF0, spart + PO1, sspart + PO1, 512,
        nullptr, 0, 64, 256, 256, 128, 128);
    stat_reduce<<<dim3(512), 64, 0, stream>>>(spart + PO1, sspart + PO1, ssum, sssum, 512, 16, OFF1);

    // L2: 3x3 s2, 64->128, 128->64. tiles 1x4=4, ocg 16 x KS2, n 8 -> 1024
    conv3s2_v2<64, 2, 8, 16, 64, 2><<<dim3(4, 32, 8), 256, 0, stream>>>(
        a1, W[2], B[2], nullptr, ssum, sssum, 1.f / 16384.f, OFF1, nullptr, nullptr, 0,
        PART, 4194304, 128, 128, 128, 64, 64);
    ksplit_reduce<<<dim3(1024), 256, 0, stream>>>(PART, B[2], a2, ssum, sssum, OFF2, 128, 4096, 4194304, 2);

    // L3: 3x3 s2, 128->256, 64->32. tile 32x32: 1 tile, ocg 32 x KS4, n 8 -> 1024
    conv3s2_v2<128, 2, 8, 32, 32, 4><<<dim3(1, 128, 8), 256, 0, stream>>>(
        a2, W[3], B[3], nullptr, ssum, sssum, 1.f / 4096.f, OFF2, nullptr, nullptr, 0,
        PART, 2097152, 256, 64, 64, 32, 32);
    ksplit_reduce<<<dim3(2048), 256, 0, stream>>>(PART, B[3], a3, ssum, sssum, OFF3, 256, 1024, 2097152, 4);

    // L4: convT, 256->128, 32->63. 1 tile, ocg 32 x KS4, n 8 -> 1024
    convt3_v2<256, 8, 4, 4><<<dim3(1, 128, 8), 256, 0, stream>>>(
        a3, W[4], B[4], nullptr, ssum, sssum, 1.f / 1024.f, OFF3, nullptr, nullptr, 0,
        PART, 4063232, 128, 32, 32, 63, 63);
    ksplit_reduce<<<dim3(1024), 256, 0, stream>>>(PART, B[4], a4, ssum, sssum, OFF4, 128, 3969, 4063232, 4);

    // L5: convT, 128->64, 63->125. tiles 2x2=4, ocg 32 (OCPT2), n 8 -> 1024
    convt3_v2<128, 8, 2, 1><<<dim3(4, 32, 8), 256, 0, stream>>>(
        a4, W[5], B[5], a5, ssum, sssum, 1.f / 3969.f, OFF4, spart + PO5, sspart + PO5, 512,
        nullptr, 0, 64, 63, 63, 125, 125);
    stat_reduce<<<dim3(512), 64, 0, stream>>>(spart + PO5, sspart + PO5, ssum, sssum, 512, 4, OFF5);

    // L6: convT, 64->32, 125->249. tiles 4x4=16, ocg 8 (OCPT4), n 8 -> 1024
    convt3_v2<64, 8, 4, 1><<<dim3(16, 8, 8), 256, 0, stream>>>(
        a5, W[6], B[6], a6, ssum, sssum, 1.f / 15625.f, OFF5, spart + PO6, sspart + PO6, 256,
        nullptr, 0, 32, 125, 125, 249, 249);
    stat_reduce<<<dim3(256), 64, 0, stream>>>(spart + PO6, sspart + PO6, ssum, sssum, 256, 16, OFF6);

    // L7: 7x7 reflect, 32->3, 249, norm-in + tanh. tiles 4x16=64, 1 ocg, n 8
    conv7_v2<32, 4, 3, true, true><<<dim3(64, 1, 8), 256, 0, stream>>>(
        a6, W[7], B[7], a7, ssum, sssum, 1.f / 62001.f, OFF6, nullptr, nullptr, 0, 3, 249, 249);

    // segment mean
    seg_accum<<<dim3(IDIV(62001, 256), 8), 256, 0, stream>>>(a7, inst, bins, 62001);
    seg_scatter<<<dim3(IDIV(62001, 256), 8), 256, 0, stream>>>(bins, inst, (float*)d_out, 62001);
}

// Round 6
// 1896.409 us; speedup vs baseline: 2.2198x; 2.2198x over previous
//
#include <hip/hip_runtime.h>
#include <math.h>

// ---------------------------------------------------------------------------
// FeatureEncoder R6: back to the R2 skeleton (direct convs, no LDS, separate
// instance-norm kernels) — R2 is the measured-best structure (1997us vs
// R3/R4/R5's 4884/3229/4210). Fixes applied to R2's known bottleneck
// (latency-serialized divergent loads, VALUBusy 12.6%):
//  * conv3s2: branchless clamped+masked loads, ICB=4 chunks -> 36 loads in
//    flight, then 288-FMA dense runs. No divergent branches in the hot loop.
//  * convT quad: ICB=4 chunks -> 16-load batches; masks as multiplies.
//  * conv7: reflect row/col indices precomputed once; 49-load batches.
//  * OCPT sized for >=1024 blocks per layer.
// ---------------------------------------------------------------------------

#define IDIV(a, b) (((a) + (b) - 1) / (b))

__device__ __forceinline__ int reflect_i(int i, int n) {
    i = i < 0 ? -i : i;
    return i >= n ? 2 * n - 2 - i : i;
}

// ---------------- 7x7 same-conv with reflect padding (pad=3) ----------------
template <int CIN, int OCPT, bool TANH>
__global__ __launch_bounds__(256) void conv7_v3(
    const float* __restrict__ x, const float* __restrict__ w,
    const float* __restrict__ b, float* __restrict__ y, int Cout, int H, int W) {
    int tx = threadIdx.x & 15, ty = threadIdx.x >> 4;
    int tilesX = IDIV(W, 16);
    int ow = (blockIdx.x % tilesX) * 16 + tx;
    int oh = (blockIdx.x / tilesX) * 16 + ty;
    int oc0 = blockIdx.y * OCPT;
    int n = blockIdx.z;
    if (ow >= W || oh >= H) return;

    // reflected input indices, computed once
    int offr[7], iws[7];
#pragma unroll
    for (int k = 0; k < 7; ++k) {
        offr[k] = reflect_i(oh + k - 3, H) * W;
        iws[k] = reflect_i(ow + k - 3, W);
    }

    float acc[OCPT];
#pragma unroll
    for (int j = 0; j < OCPT; ++j) acc[j] = 0.f;

    const float* xn = x + (size_t)n * CIN * H * W;
    for (int ic = 0; ic < CIN; ++ic) {
        const float* xp = xn + (size_t)ic * H * W;
        float v[49];
#pragma unroll
        for (int kh = 0; kh < 7; ++kh) {
#pragma unroll
            for (int kw = 0; kw < 7; ++kw)
                v[kh * 7 + kw] = xp[offr[kh] + iws[kw]];
        }
        const float* wp = w + ((size_t)oc0 * CIN + ic) * 49;
#pragma unroll
        for (int j = 0; j < OCPT; ++j) {
#pragma unroll
            for (int t = 0; t < 49; ++t)
                acc[j] += v[t] * wp[(size_t)j * CIN * 49 + t];
        }
    }
#pragma unroll
    for (int j = 0; j < OCPT; ++j) {
        float r = acc[j] + b[oc0 + j];
        if (TANH) r = tanhf(r);
        y[(((size_t)n * Cout + oc0 + j) * H + oh) * W + ow] = r;
    }
}

// ---------------- 3x3 stride-2 pad-1 conv, branchless batched loads ----------
template <int CIN, int ICB, int OCPT>
__global__ __launch_bounds__(256) void conv3s2_v3(
    const float* __restrict__ x, const float* __restrict__ w,
    const float* __restrict__ b, float* __restrict__ y,
    int Cout, int Hin, int Win, int Hout, int Wout) {
    int tx = threadIdx.x & 15, ty = threadIdx.x >> 4;
    int tilesX = Wout >> 4;
    int ow = (blockIdx.x % tilesX) * 16 + tx;
    int oh = (blockIdx.x / tilesX) * 16 + ty;
    int oc0 = blockIdx.y * OCPT;
    int n = blockIdx.z;

    int ih0 = oh * 2 - 1, iw0 = ow * 2 - 1;
    // clamped offsets + masks (only -1 underflow can occur for these shapes,
    // but keep the general clamp)
    int off[9];
    float mm[9];
#pragma unroll
    for (int kh = 0; kh < 3; ++kh) {
        int ih = ih0 + kh;
        int ihc = min(max(ih, 0), Hin - 1);
        float mr = (ih >= 0 && ih < Hin) ? 1.f : 0.f;
#pragma unroll
        for (int kw = 0; kw < 3; ++kw) {
            int iw = iw0 + kw;
            int iwc = min(max(iw, 0), Win - 1);
            float mc = (iw >= 0 && iw < Win) ? 1.f : 0.f;
            off[kh * 3 + kw] = ihc * Win + iwc;
            mm[kh * 3 + kw] = mr * mc;
        }
    }

    float acc[OCPT];
#pragma unroll
    for (int j = 0; j < OCPT; ++j) acc[j] = 0.f;

    const float* xn = x + (size_t)n * CIN * Hin * Win;
    for (int ic0 = 0; ic0 < CIN; ic0 += ICB) {
        float v[ICB][9];
#pragma unroll
        for (int icl = 0; icl < ICB; ++icl) {
            const float* xp = xn + (size_t)(ic0 + icl) * Hin * Win;
#pragma unroll
            for (int t = 0; t < 9; ++t) v[icl][t] = xp[off[t]] * mm[t];
        }
#pragma unroll
        for (int icl = 0; icl < ICB; ++icl) {
            const float* wp = w + ((size_t)oc0 * CIN + ic0 + icl) * 9;
#pragma unroll
            for (int j = 0; j < OCPT; ++j) {
#pragma unroll
                for (int t = 0; t < 9; ++t)
                    acc[j] += v[icl][t] * wp[(size_t)j * CIN * 9 + t];
            }
        }
    }
#pragma unroll
    for (int j = 0; j < OCPT; ++j)
        y[(((size_t)n * Cout + oc0 + j) * Hout + oh) * Wout + ow] = acc[j] + b[oc0 + j];
}

// ---------------- 3x3 s2 transposed conv, 2x2 quad, batched loads ------------
// torch weight layout w[Cin][Cout][3][3]; output quad at (2qy,2qx).
template <int CIN, int ICB, int OCPT>
__global__ __launch_bounds__(256) void convt3_v3(
    const float* __restrict__ x, const float* __restrict__ w,
    const float* __restrict__ b, float* __restrict__ y,
    int Cout, int Hin, int Win, int Hout, int Wout) {
    int tx = threadIdx.x & 15, ty = threadIdx.x >> 4;
    int tilesX = IDIV(Win, 16);
    int qx = (blockIdx.x % tilesX) * 16 + tx;
    int qy = (blockIdx.x / tilesX) * 16 + ty;
    int oc0 = blockIdx.y * OCPT;
    int n = blockIdx.z;
    if (qx >= Win || qy >= Hin) return;
    bool xin = (qx + 1 < Win), yin = (qy + 1 < Hin);
    int o01 = xin ? 1 : 0, o10 = yin ? Win : 0;
    int o11 = o01 + o10;
    float m01 = xin ? 1.f : 0.f, m10 = yin ? 1.f : 0.f, m11 = m01 * m10;

    float a00[OCPT], a01[OCPT], a10[OCPT], a11[OCPT];
#pragma unroll
    for (int j = 0; j < OCPT; ++j) { a00[j] = a01[j] = a10[j] = a11[j] = 0.f; }

    const float* xn = x + ((size_t)n * CIN) * Hin * Win + (size_t)qy * Win + qx;
    for (int ic0 = 0; ic0 < CIN; ic0 += ICB) {
        float v[ICB][4];
#pragma unroll
        for (int icl = 0; icl < ICB; ++icl) {
            const float* xp = xn + (size_t)(ic0 + icl) * Hin * Win;
            v[icl][0] = xp[0];
            v[icl][1] = xp[o01] * m01;
            v[icl][2] = xp[o10] * m10;
            v[icl][3] = xp[o11] * m11;
        }
#pragma unroll
        for (int icl = 0; icl < ICB; ++icl) {
            const float* wp = w + ((size_t)(ic0 + icl) * Cout + oc0) * 9;
#pragma unroll
            for (int j = 0; j < OCPT; ++j) {
                const float* wj = wp + j * 9;
                float w0 = wj[0], w1 = wj[1], w2 = wj[2];
                float w3 = wj[3], w4 = wj[4], w5 = wj[5];
                float w6 = wj[6], w7 = wj[7], w8 = wj[8];
                a00[j] += w4 * v[icl][0];
                a01[j] += w5 * v[icl][0] + w3 * v[icl][1];
                a10[j] += w7 * v[icl][0] + w1 * v[icl][2];
                a11[j] += w8 * v[icl][0] + w6 * v[icl][1] + w2 * v[icl][2] + w0 * v[icl][3];
            }
        }
    }

    int oh = 2 * qy, ow = 2 * qx;
#pragma unroll
    for (int j = 0; j < OCPT; ++j) {
        float bb = b[oc0 + j];
        float* yp = y + (((size_t)n * Cout + oc0 + j) * Hout + oh) * Wout + ow;
        yp[0] = a00[j] + bb;
        if (xin) yp[1] = a01[j] + bb;
        if (yin) yp[Wout] = a10[j] + bb;
        if (xin && yin) yp[Wout + 1] = a11[j] + bb;
    }
}

// ---------------- instance norm: stats (sum, sumsq -> mean, inv) ------------
__global__ void inorm_stats(const float* __restrict__ x, float* __restrict__ mean,
                            float* __restrict__ inv, int plane) {
    int pc = blockIdx.x;
    const float* p = x + (size_t)pc * plane;
    float s = 0.f, ss = 0.f;
    for (int i = threadIdx.x; i < plane; i += 256) {
        float v = p[i];
        s += v;
        ss += v * v;
    }
#pragma unroll
    for (int o = 32; o > 0; o >>= 1) {
        s += __shfl_down(s, o);
        ss += __shfl_down(ss, o);
    }
    __shared__ float sh[8];
    int wid = threadIdx.x >> 6;
    if ((threadIdx.x & 63) == 0) { sh[wid] = s; sh[4 + wid] = ss; }
    __syncthreads();
    if (threadIdx.x == 0) {
        s = sh[0] + sh[1] + sh[2] + sh[3];
        ss = sh[4] + sh[5] + sh[6] + sh[7];
        float m = s / plane;
        float var = ss / plane - m * m;
        mean[pc] = m;
        inv[pc] = rsqrtf(var + 1e-5f);
    }
}

// ---------------- instance norm apply + relu (in place) ----------------
__global__ void inorm_apply(float* __restrict__ x, const float* __restrict__ mean,
                            const float* __restrict__ inv, int plane) {
    int pc = blockIdx.y;
    int i = blockIdx.x * 256 + threadIdx.x;
    if (i >= plane) return;
    float m = mean[pc], iv = inv[pc];
    size_t idx = (size_t)pc * plane + i;
    float v = x[idx];
    x[idx] = fmaxf(0.f, (v - m) * iv);
}

// ---------------- segment mean ----------------
__global__ void seg_zero(float* __restrict__ bins) {
    if (threadIdx.x < 128) bins[threadIdx.x] = 0.f;
}

__global__ void seg_accum(const float* __restrict__ a7, const int* __restrict__ inst,
                          float* __restrict__ bins, int HW) {
    __shared__ float ls[128];  // 96 sums + 32 counts
    for (int i = threadIdx.x; i < 128; i += 256) ls[i] = 0.f;
    __syncthreads();
    int n = blockIdx.y;
    int i = blockIdx.x * 256 + threadIdx.x;
    if (i < HW) {
        int id = inst[(size_t)n * HW + i];
        const float* p = a7 + (size_t)n * 3 * HW + i;
        atomicAdd(&ls[id * 3 + 0], p[0]);
        atomicAdd(&ls[id * 3 + 1], p[HW]);
        atomicAdd(&ls[id * 3 + 2], p[2 * (size_t)HW]);
        atomicAdd(&ls[96 + id], 1.0f);
    }
    __syncthreads();
    for (int i2 = threadIdx.x; i2 < 128; i2 += 256)
        if (ls[i2] != 0.f) atomicAdd(&bins[i2], ls[i2]);
}

__global__ void seg_scatter(const float* __restrict__ bins, const int* __restrict__ inst,
                            float* __restrict__ out, int HW) {
    int n = blockIdx.y;
    int i = blockIdx.x * 256 + threadIdx.x;
    if (i >= HW) return;
    int id = inst[(size_t)n * HW + i];
    float c = fmaxf(bins[96 + id], 1.0f);
    out[((size_t)n * 3 + 0) * HW + i] = bins[id * 3 + 0] / c;
    out[((size_t)n * 3 + 1) * HW + i] = bins[id * 3 + 1] / c;
    out[((size_t)n * 3 + 2) * HW + i] = bins[id * 3 + 2] / c;
}

// ---------------------------------------------------------------------------
extern "C" void kernel_launch(void* const* d_in, const int* in_sizes, int n_in,
                              void* d_out, int out_size, void* d_ws, size_t ws_size,
                              hipStream_t stream) {
    const float* x = (const float*)d_in[0];
    const int* inst = (const int*)d_in[1];
    const float* W[8];
    const float* B[8];
    for (int i = 0; i < 8; ++i) {
        W[i] = (const float*)d_in[2 + 2 * i];
        B[i] = (const float*)d_in[3 + 2 * i];
    }
    float* ws = (float*)d_ws;

    // End-aligned ping-pong arena (same as R2, proven)
    const size_t S = 25165824;  // floats
    float* a0 = ws;                  // [8,32,256,256]
    float* a1 = ws + 16777216;       // [8,64,128,128]
    float* a2 = ws;                  // [8,128,64,64]
    float* a3 = ws + 23068672;       // [8,256,32,32]
    float* a4 = ws;                  // [8,128,63,63]
    float* a5 = ws + 17165824;       // [8,64,125,125]
    float* a6 = ws;                  // [8,32,249,249]
    float* a7 = ws + 23677800;       // [8,3,249,249]
    float* mean = ws + S;            // 2048
    float* inv = mean + 2048;        // 2048
    float* bins = inv + 2048;        // 128

    auto inorm = [&](float* buf, int planes, int plane) {
        inorm_stats<<<dim3(planes), 256, 0, stream>>>(buf, mean, inv, plane);
        inorm_apply<<<dim3(IDIV(plane, 256), planes), 256, 0, stream>>>(buf, mean, inv, plane);
    };

    // L0: 7x7 reflect, 3->32, 256. 256 tiles x 4 ocg x 8 n = 8192 blocks
    conv7_v3<3, 8, false><<<dim3(256, 4, 8), 256, 0, stream>>>(x, W[0], B[0], a0, 32, 256, 256);
    inorm(a0, 8 * 32, 65536);
    // L1: 3x3 s2, 32->64, 256->128. 64 x 8 x 8 = 4096 blocks
    conv3s2_v3<32, 4, 8><<<dim3(64, 8, 8), 256, 0, stream>>>(a0, W[1], B[1], a1, 64, 256, 256, 128, 128);
    inorm(a1, 8 * 64, 16384);
    // L2: 3x3 s2, 64->128, 128->64. 16 x 16 x 8 = 2048 blocks
    conv3s2_v3<64, 4, 8><<<dim3(16, 16, 8), 256, 0, stream>>>(a1, W[2], B[2], a2, 128, 128, 128, 64, 64);
    inorm(a2, 8 * 128, 4096);
    // L3: 3x3 s2, 128->256, 64->32. 4 x 32 x 8 = 1024 blocks
    conv3s2_v3<128, 4, 8><<<dim3(4, 32, 8), 256, 0, stream>>>(a2, W[3], B[3], a3, 256, 64, 64, 32, 32);
    inorm(a3, 8 * 256, 1024);
    // L4: convT, 256->128, 32->63. quad 32x32: 4 tiles x 32 ocg x 8 = 1024 blocks
    convt3_v3<256, 4, 4><<<dim3(4, 32, 8), 256, 0, stream>>>(a3, W[4], B[4], a4, 128, 32, 32, 63, 63);
    inorm(a4, 8 * 128, 3969);
    // L5: convT, 128->64, 63->125. quad 63x63: 16 tiles x 16 ocg x 8 = 2048 blocks
    convt3_v3<128, 4, 4><<<dim3(16, 16, 8), 256, 0, stream>>>(a4, W[5], B[5], a5, 64, 63, 63, 125, 125);
    inorm(a5, 8 * 64, 15625);
    // L6: convT, 64->32, 125->249. quad 125x125: 64 tiles x 8 ocg x 8 = 4096 blocks
    convt3_v3<64, 4, 4><<<dim3(64, 8, 8), 256, 0, stream>>>(a5, W[6], B[6], a6, 32, 125, 125, 249, 249);
    inorm(a6, 8 * 32, 62001);
    // L7: 7x7 reflect, 32->3, 249, tanh. 256 tiles x 1 x 8 = 2048 blocks
    conv7_v3<32, 3, true><<<dim3(256, 1, 8), 256, 0, stream>>>(a6, W[7], B[7], a7, 3, 249, 249);

    // segment mean
    seg_zero<<<1, 128, 0, stream>>>(bins);
    seg_accum<<<dim3(IDIV(62001, 256), 8), 256, 0, stream>>>(a7, inst, bins, 62001);
    seg_scatter<<<dim3(IDIV(62001, 256), 8), 256, 0, stream>>>(bins, inst, (float*)d_out, 62001);
}